// Round 6
// baseline (266.451 us; speedup 1.0000x reference)
//
#include <hip/hip_runtime.h>

#define C_IN     7
#define D_MODEL  512
#define TAO      3
#define M_TAPS   5
#define KERNELS  73            // D_MODEL / C_IN
#define B_SZ     32
#define L_SZ     4096
#define TB       64            // t-positions per block
#define NTB      (L_SZ / TB)   // 64
#define ROWS     (TB + 17)     // 81 staged rows (16 back-halo + 1 forward)
#define RPAD     84

__global__ __launch_bounds__(256, 4) void trc_conv_kernel(
    const float* __restrict__ x,          // [B, L, C_IN]
    const float* __restrict__ conv_w,     // [73, 6, 3]
    const float* __restrict__ conv_b,     // [73]
    const float* __restrict__ leftout_w,  // [1, 6, 3]
    const float* __restrict__ leftout_b,  // [1]
    float* __restrict__ out)              // [B, L, 512]
{
    __shared__ float xs[C_IN][RPAD];
    const int tid = threadIdx.x;
    const int b   = blockIdx.x / NTB;
    const int tb  = blockIdx.x % NTB;
    const int t0  = tb * TB;

    // Stage x rows [t0-16, t0+TB] (circular) into LDS, transposed [ch][row].
    const float* xb = x + (size_t)b * L_SZ * C_IN;
    for (int i = tid; i < ROWS * C_IN; i += 256) {
        int r = i / C_IN, c = i - r * C_IN;
        int g = t0 - 16 + r;
        if (g < 0)      g += L_SZ;
        if (g >= L_SZ)  g -= L_SZ;
        xs[c][r] = xb[(size_t)g * C_IN + c];
    }
    __syncthreads();

    // Each thread owns the adjacent pair d0 = 2*tid, d1 = d0+1 (float2 store).
    const int d0 = 2 * tid, d1 = d0 + 1;

    int ch0, ch1;
    const float *ws0, *ws1;
    float bias0, bias1;
    if (d0 < C_IN * KERNELS) { ch0 = d0 / KERNELS; int o = d0 - ch0 * KERNELS; ws0 = conv_w + o * 18; bias0 = conv_b[o]; }
    else                     { ch0 = C_IN - 1; ws0 = leftout_w; bias0 = leftout_b[0]; }
    if (d1 < C_IN * KERNELS) { ch1 = d1 / KERNELS; int o = d1 - ch1 * KERNELS; ws1 = conv_w + o * 18; bias1 = conv_b[o]; }
    else                     { ch1 = C_IN - 1; ws1 = leftout_w; bias1 = leftout_b[0]; }

    const float* __restrict__ rowA = &xs[ch0][0];
    const float* __restrict__ rowB = &xs[ch1][0];

    // FIR weights by row-offset j (0 = oldest = row t-16): k=j%3, m=(15+k-j)/3.
    float wa[18], wb[18];
    #pragma unroll
    for (int j = 0; j < 18; ++j) {
        int k = j % 3;
        int m = (15 + k - j) / 3;
        wa[j] = ws0[m * 3 + k];
        wb[j] = ws1[m * 3 + k];
    }

    const bool first = (tb == 0), last = (tb == NTB - 1);

    // Masked edge-row evaluation (wrap + validity), same arithmetic as R5.
    auto edge = [&](const float* __restrict__ row, const float* __restrict__ w,
                    float bias, int tl) -> float {
        float acc = bias;
        #pragma unroll
        for (int k = 0; k < 3; ++k) {
            int tt = t0 + tl + k - 1;
            if (tt < 0)      tt += L_SZ;
            if (tt >= L_SZ)  tt -= L_SZ;
            if (tt >= M_TAPS * TAO) {
                int lt = tl + 15 + k;
                #pragma unroll
                for (int m = 0; m < 6; ++m)
                    acc = fmaf(row[lt - 3 * m], w[15 + k - 3 * m], acc);
            }
        }
        return acc;
    };

    float2* outv = (float2*)(out + ((size_t)b * L_SZ + t0) * D_MODEL) + tid;

    // Dual sliding register windows (one per output), no barriers, direct
    // float2 stores: wave = 512 B contiguous, waves free-run.
    float winA[18], winB[18];
    #pragma unroll
    for (int j = 0; j < 17; ++j) { winA[j] = rowA[j]; winB[j] = rowB[j]; }

    #pragma unroll
    for (int tl = 0; tl < TB; ++tl) {
        winA[(tl + 17) % 18] = rowA[tl + 17];
        winB[(tl + 17) % 18] = rowB[tl + 17];
        float a0, a1;
        if ((first && tl < 16) || (last && tl == TB - 1)) {
            a0 = edge(rowA, wa, bias0, tl);
            a1 = edge(rowB, wb, bias1, tl);
        } else {
            a0 = bias0; a1 = bias1;
            #pragma unroll
            for (int j = 0; j < 18; ++j) {
                a0 = fmaf(winA[(tl + j) % 18], wa[j], a0);
                a1 = fmaf(winB[(tl + j) % 18], wb[j], a1);
            }
        }
        outv[(size_t)tl * (D_MODEL / 2)] = make_float2(a0, a1);
    }
}

extern "C" void kernel_launch(void* const* d_in, const int* in_sizes, int n_in,
                              void* d_out, int out_size, void* d_ws, size_t ws_size,
                              hipStream_t stream) {
    const float* x          = (const float*)d_in[0];
    const float* conv_w     = (const float*)d_in[1];
    const float* conv_b     = (const float*)d_in[2];
    const float* leftout_w  = (const float*)d_in[3];
    const float* leftout_b  = (const float*)d_in[4];
    float* out = (float*)d_out;

    dim3 grid(B_SZ * NTB);   // 2048 blocks x 256 threads
    trc_conv_kernel<<<grid, 256, 0, stream>>>(x, conv_w, conv_b,
                                              leftout_w, leftout_b, out);
}

// Round 7
// 87.761 us; speedup vs baseline: 3.0361x; 3.0361x over previous
//
#include <hip/hip_runtime.h>

#define C_IN     7
#define D_MODEL  512
#define TAO      3
#define M_TAPS   5
#define KERNELS  73            // D_MODEL / C_IN
#define B_SZ     32
#define L_SZ     4096
#define TB       64            // t-positions per block
#define NTB      (L_SZ / TB)   // 64
#define ROWS     (TB + 17)     // 81 staged rows (16 back-halo + 1 forward)
#define RPAD     84

__global__ __launch_bounds__(256, 2) void trc_conv_kernel(
    const float* __restrict__ x,          // [B, L, C_IN]
    const float* __restrict__ conv_w,     // [73, 6, 3]
    const float* __restrict__ conv_b,     // [73]
    const float* __restrict__ leftout_w,  // [1, 6, 3]
    const float* __restrict__ leftout_b,  // [1]
    float* __restrict__ out)              // [B, L, 512]
{
    __shared__ float xs[C_IN][RPAD];
    const int tid = threadIdx.x;
    const int b   = blockIdx.x / NTB;
    const int tb  = blockIdx.x % NTB;
    const int t0  = tb * TB;

    // Stage x rows [t0-16, t0+TB] (circular) into LDS, transposed [ch][row].
    const float* xb = x + (size_t)b * L_SZ * C_IN;
    for (int i = tid; i < ROWS * C_IN; i += 256) {
        int r = i / C_IN, c = i - r * C_IN;
        int g = t0 - 16 + r;
        if (g < 0)      g += L_SZ;
        if (g >= L_SZ)  g -= L_SZ;
        xs[c][r] = xb[(size_t)g * C_IN + c];
    }
    __syncthreads();

    // Each thread owns the adjacent pair d0 = 2*tid, d1 = d0+1 (float2 store).
    const int d0 = 2 * tid, d1 = d0 + 1;

    int ch0, ch1;
    const float *ws0, *ws1;
    float bias0, bias1;
    if (d0 < C_IN * KERNELS) { ch0 = d0 / KERNELS; int o = d0 - ch0 * KERNELS; ws0 = conv_w + o * 18; bias0 = conv_b[o]; }
    else                     { ch0 = C_IN - 1; ws0 = leftout_w; bias0 = leftout_b[0]; }
    if (d1 < C_IN * KERNELS) { ch1 = d1 / KERNELS; int o = d1 - ch1 * KERNELS; ws1 = conv_w + o * 18; bias1 = conv_b[o]; }
    else                     { ch1 = C_IN - 1; ws1 = leftout_w; bias1 = leftout_b[0]; }

    const float* __restrict__ rowA = &xs[ch0][0];
    const float* __restrict__ rowB = &xs[ch1][0];

    // FIR weights by row-offset j (0 = oldest = row t-16): k=j%3, m=(15+k-j)/3.
    float wa[18], wb[18];
    #pragma unroll
    for (int j = 0; j < 18; ++j) {
        int k = j % 3;
        int m = (15 + k - j) / 3;
        wa[j] = ws0[m * 3 + k];
        wb[j] = ws1[m * 3 + k];
    }

    float2* outv = (float2*)(out + ((size_t)b * L_SZ + t0) * D_MODEL) + tid;

    if (tb == 0 || tb == NTB - 1) {
        // Edge blocks (2/64): masked path, direct LDS reads, no register arrays.
        for (int tl = 0; tl < TB; ++tl) {
            float a0 = bias0, a1 = bias1;
            #pragma unroll
            for (int k = 0; k < 3; ++k) {
                int tt = t0 + tl + k - 1;
                if (tt < 0)      tt += L_SZ;
                if (tt >= L_SZ)  tt -= L_SZ;
                if (tt >= M_TAPS * TAO) {
                    int lt = tl + 15 + k;
                    #pragma unroll
                    for (int m = 0; m < 6; ++m) {
                        a0 = fmaf(rowA[lt - 3 * m], wa[15 + k - 3 * m], a0);
                        a1 = fmaf(rowB[lt - 3 * m], wb[15 + k - 3 * m], a1);
                    }
                }
            }
            outv[(size_t)tl * (D_MODEL / 2)] = make_float2(a0, a1);
        }
        return;
    }

    // Interior blocks: dual static-shift windows, 16 outputs/chunk, no
    // barriers, direct float2 stores (wave = 512 B contiguous, free-running).
    // All register indices compile-time (outer chunk loop is runtime — only
    // LDS reads depend on it).
    float winA[33], winB[33];
    #pragma unroll
    for (int q = 0; q < 17; ++q) { winA[q] = rowA[q]; winB[q] = rowB[q]; }

    for (int c = 0; c < TB; c += 16) {
        #pragma unroll
        for (int i = 0; i < 16; ++i) {
            winA[17 + i] = rowA[c + 17 + i];
            winB[17 + i] = rowB[c + 17 + i];
        }
        #pragma unroll
        for (int i = 0; i < 16; ++i) {
            float a0 = bias0, a1 = bias1;
            #pragma unroll
            for (int j = 0; j < 18; ++j) {
                a0 = fmaf(winA[i + j], wa[j], a0);
                a1 = fmaf(winB[i + j], wb[j], a1);
            }
            outv[(size_t)(c + i) * (D_MODEL / 2)] = make_float2(a0, a1);
        }
        #pragma unroll
        for (int q = 0; q < 17; ++q) { winA[q] = winA[q + 16]; winB[q] = winB[q + 16]; }
    }
}

extern "C" void kernel_launch(void* const* d_in, const int* in_sizes, int n_in,
                              void* d_out, int out_size, void* d_ws, size_t ws_size,
                              hipStream_t stream) {
    const float* x          = (const float*)d_in[0];
    const float* conv_w     = (const float*)d_in[1];
    const float* conv_b     = (const float*)d_in[2];
    const float* leftout_w  = (const float*)d_in[3];
    const float* leftout_b  = (const float*)d_in[4];
    float* out = (float*)d_out;

    dim3 grid(B_SZ * NTB);   // 2048 blocks x 256 threads
    trc_conv_kernel<<<grid, 256, 0, stream>>>(x, conv_w, conv_b,
                                              leftout_w, leftout_b, out);
}

// Round 8
// 50.035 us; speedup vs baseline: 5.3253x; 1.7540x over previous
//
#include <hip/hip_runtime.h>

#define C_IN     7
#define D_MODEL  512
#define TAO      3
#define M_TAPS   5
#define KERNELS  73            // D_MODEL / C_IN
#define B_SZ     32
#define L_SZ     4096
#define TB       64            // t-positions per block
#define NTB      (L_SZ / TB)   // 64
#define ROWS     (TB + 17)     // 81 staged rows
#define RPAD     84
#define CHUNK    8             // rows per wave-local chunk
#define NCH      (TB / CHUNK)  // 8

__global__ __launch_bounds__(512, 6) void trc_conv_kernel(
    const float* __restrict__ x,          // [B, L, C_IN]
    const float* __restrict__ conv_w,     // [73, 6, 3]
    const float* __restrict__ conv_b,     // [73]
    const float* __restrict__ leftout_w,  // [1, 6, 3]
    const float* __restrict__ leftout_b,  // [1]
    float* __restrict__ out)              // [B, L, 512]
{
    __shared__ float xs[C_IN][RPAD];
    __shared__ __align__(16) float buf[8][2][CHUNK][64];  // per-wave double-buffered out-tiles (32 KB)

    const int tid = threadIdx.x;
    const int wv  = tid >> 6;        // wave id 0..7 -> owns cols [64*wv, 64*wv+64)
    const int ln  = tid & 63;
    const int b   = blockIdx.x / NTB;
    const int tb  = blockIdx.x % NTB;
    const int t0  = tb * TB;

    // Stage x rows [t0-16, t0+TB] (circular) into LDS, transposed [ch][row].
    const float* xb = x + (size_t)b * L_SZ * C_IN;
    for (int i = tid; i < ROWS * C_IN; i += 512) {
        int r = i / C_IN, c = i - r * C_IN;
        int g = t0 - 16 + r;
        if (g < 0)      g += L_SZ;
        if (g >= L_SZ)  g -= L_SZ;
        xs[c][r] = xb[(size_t)g * C_IN + c];
    }
    __syncthreads();   // the ONLY barrier

    // Column ownership: d = 64*wv + ln (== tid).
    const int d = tid;
    int ch;
    const float* wsrc;
    float bias;
    if (d < C_IN * KERNELS) {
        ch = d / KERNELS;
        int o = d - ch * KERNELS;
        wsrc = conv_w + o * 18;
        bias = conv_b[o];
    } else {
        ch = C_IN - 1;
        wsrc = leftout_w;
        bias = leftout_b[0];
    }
    const float* __restrict__ row = &xs[ch][0];

    // FIR weights by row-offset j (0 = oldest = row t-16): k=j%3, m=(15+k-j)/3.
    float wreg[18];
    #pragma unroll
    for (int j = 0; j < 18; ++j) {
        int k = j % 3;
        int m = (15 + k - j) / 3;
        wreg[j] = wsrc[m * 3 + k];
    }

    const bool first = (tb == 0), last = (tb == NTB - 1);

    // Masked edge-row evaluation (wrap + validity).
    auto edge_eval = [&](int tl) -> float {
        float acc = bias;
        #pragma unroll
        for (int k = 0; k < 3; ++k) {
            int tt = t0 + tl + k - 1;
            if (tt < 0)      tt += L_SZ;
            if (tt >= L_SZ)  tt -= L_SZ;
            if (tt >= M_TAPS * TAO) {
                int lt = tl + 15 + k;
                #pragma unroll
                for (int m = 0; m < 6; ++m)
                    acc = fmaf(row[lt - 3 * m], wreg[15 + k - 3 * m], acc);
            }
        }
        return acc;
    };

    float* __restrict__ bufw = &buf[wv][0][0][0];        // 2*CHUNK*64 floats, wave-private
    const int lrow = ln >> 4, lcol = ln & 15;            // store lane mapping
    float4* base4 = (float4*)(out + ((size_t)b * L_SZ + t0) * D_MODEL + wv * 64) ;

    // Sliding window (static indices only), chunk = 8 rows.
    float win[25];
    #pragma unroll
    for (int q = 0; q < 17; ++q) win[q] = row[q];

    float4 r0, r1;

    for (int c = 0; c < NCH; ++c) {
        float* __restrict__ bc = bufw + (c & 1) * (CHUNK * 64);

        #pragma unroll
        for (int i = 0; i < CHUNK; ++i) win[17 + i] = row[c * CHUNK + 17 + i];
        #pragma unroll
        for (int i = 0; i < CHUNK; ++i) {
            float acc = bias;
            #pragma unroll
            for (int j = 0; j < 18; ++j)
                acc = fmaf(win[i + j], wreg[j], acc);
            bc[i * 64 + ln] = acc;                        // stride-1: conflict-free
        }
        #pragma unroll
        for (int q = 0; q < 17; ++q) win[q] = win[q + 8];

        // Cold edge fix-ups (block-uniform branches; 2/64 blocks only).
        if (first && c < 2) {
            for (int i = 0; i < CHUNK; ++i)
                bc[i * 64 + ln] = edge_eval(c * CHUNK + i);   // tl = 0..15 all masked
        }
        if (last && c == NCH - 1) {
            bc[(CHUNK - 1) * 64 + ln] = edge_eval(TB - 1);
        }

        // Issue read-back of THIS chunk; consume (store) it next iteration,
        // so DS latency hides under the next chunk's FMA block.
        const float4* bv = (const float4*)bc;
        float4 n0 = bv[ln];          // rows 0..3 of chunk, col 4*lcol
        float4 n1 = bv[ln + 64];     // rows 4..7
        __builtin_amdgcn_sched_barrier(0);

        if (c > 0) {
            base4[(size_t)((c - 1) * CHUNK + 0 + lrow) * (D_MODEL / 4) + lcol] = r0;
            base4[(size_t)((c - 1) * CHUNK + 4 + lrow) * (D_MODEL / 4) + lcol] = r1;
        }
        r0 = n0; r1 = n1;
    }
    base4[(size_t)((NCH - 1) * CHUNK + 0 + lrow) * (D_MODEL / 4) + lcol] = r0;
    base4[(size_t)((NCH - 1) * CHUNK + 4 + lrow) * (D_MODEL / 4) + lcol] = r1;
}

extern "C" void kernel_launch(void* const* d_in, const int* in_sizes, int n_in,
                              void* d_out, int out_size, void* d_ws, size_t ws_size,
                              hipStream_t stream) {
    const float* x          = (const float*)d_in[0];
    const float* conv_w     = (const float*)d_in[1];
    const float* conv_b     = (const float*)d_in[2];
    const float* leftout_w  = (const float*)d_in[3];
    const float* leftout_b  = (const float*)d_in[4];
    float* out = (float*)d_out;

    dim3 grid(B_SZ * NTB);   // 2048 blocks x 512 threads
    trc_conv_kernel<<<grid, 512, 0, stream>>>(x, conv_w, conv_b,
                                              leftout_w, leftout_b, out);
}